// Round 2
// baseline (71.167 us; speedup 1.0000x reference)
//
#include <hip/hip_runtime.h>
#include <math.h>

// QuantumLayer — analytic collapse of the 16-qubit, 3-layer circuit.
//
// Math (verified against the reference's gate ordering):
//  * RY layer on |0…0> -> product state; per-qubit E[Z_q]=cos(theta_q).
//  * RZ-phase diagonals are unit-modulus -> cancel in |psi|^2 (q_weights unused).
//  * The CNOT chain is GF(2)-linear; after 3 layers the measured distribution
//    is the initial product distribution relabeled by L^3, whose row-q support
//    is {k<=q : (q-k) mod 4 in {0,1}}.
//  => expvals[b,q] = prod_{k<=q,(q-k)%4<2} cos(theta[b,k])
//     theta = x@W_in.T + b_in ; out = ev@W_out.T + b_out.
//
// Structure: one wave per batch row, fully register-resident.
//  - butterfly __shfl_xor reduce -> every lane holds all 16 thetas
//  - no LDS, no __syncthreads, grid 64 x 256 (4 independent waves/block)
// ~2 MFLOP total; timed duration is dominated by the harness's 256 MB
// workspace re-poison fill (~39 us @ 85% HBM peak), not this kernel.

#define BATCH 256
#define DDIM  128
#define NQ    16

__global__ __launch_bounds__(256) void qlayer_kernel(
    const float* __restrict__ x,     // (256,128)
    const float* __restrict__ Win,   // (16,128)
    const float* __restrict__ bin,   // (16)
    const float* __restrict__ Wout,  // (128,16)
    const float* __restrict__ bout,  // (128)
    float* __restrict__ out)         // (256,128)
{
    const int wave = threadIdx.x >> 6;
    const int lane = threadIdx.x & 63;
    const int row  = blockIdx.x * 4 + wave;   // one wave = one batch row

    // Each lane owns 2 of the 128 x-elements (coalesced).
    const float x0 = x[row * DDIM + lane];
    const float x1 = x[row * DDIM + lane + 64];

    // theta[q] via butterfly reduce -> all lanes hold the full sum.
    float c[NQ];
    #pragma unroll
    for (int q = 0; q < NQ; ++q) {
        float p = x0 * Win[q * DDIM + lane] + x1 * Win[q * DDIM + lane + 64];
        #pragma unroll
        for (int off = 1; off < 64; off <<= 1)
            p += __shfl_xor(p, off, 64);
        c[q] = cosf(p + bin[q]);
    }

    // ev[q] = prod_{k<=q, (q-k)%4 in {0,1}} cos(theta[k])  (masks fold at compile time)
    float ev[NQ];
    #pragma unroll
    for (int q = 0; q < NQ; ++q) {
        float e = 1.0f;
        #pragma unroll
        for (int k = 0; k <= q; ++k)
            if (((q - k) & 3) < 2) e *= c[k];
        ev[q] = e;
    }

    // out[row,d] = b_out[d] + <ev, W_out[d,:]> ; each lane emits 2 outputs.
    #pragma unroll
    for (int r = 0; r < 2; ++r) {
        const int d = lane + 64 * r;
        float acc = bout[d];
        const float4* w4 = (const float4*)(Wout + d * NQ);
        #pragma unroll
        for (int j = 0; j < 4; ++j) {
            const float4 w = w4[j];
            acc += ev[4 * j]     * w.x + ev[4 * j + 1] * w.y
                 + ev[4 * j + 2] * w.z + ev[4 * j + 3] * w.w;
        }
        out[row * DDIM + d] = acc;
    }
}

extern "C" void kernel_launch(void* const* d_in, const int* in_sizes, int n_in,
                              void* d_out, int out_size, void* d_ws, size_t ws_size,
                              hipStream_t stream) {
    const float* x    = (const float*)d_in[0];
    const float* Win  = (const float*)d_in[1];
    const float* bin  = (const float*)d_in[2];
    // d_in[3] = q_weights: provably unused — RZ phases cancel in |psi|^2.
    const float* Wout = (const float*)d_in[4];
    const float* bout = (const float*)d_in[5];
    float* out = (float*)d_out;

    qlayer_kernel<<<BATCH / 4, 256, 0, stream>>>(x, Win, bin, Wout, bout, out);
}